// Round 1
// 76.147 us; speedup vs baseline: 1.0086x; 1.0086x over previous
//
#include <hip/hip_runtime.h>

// SpectralConv2D_T: B=64,H=32,W=32,C=8, F=64,K=3, VALID/stride1 -> O=30x30, L=900, N=1024
// out[b,r,c,f] = relu( S1 - dec[l]*S2 ),  S1=conv3x3(ue), S2=conv3x3(up), ue=up*enc,
// up = channel-mean of inputs. w[f,i,j] = omega[f,i,j]*(lam_in[i]-lam_out[j]);
// omega from diag (F,3), triu order (0,1),(0,2),(1,2), tril order (1,0),(2,0),(2,1).
//
// Layout: grid = 64 images x 15 row-pair stripes (960 blocks); block = 256 (4 waves).
// Each block stages ONLY the 4 input rows its stripe needs (4KB, fully-coalesced
// float4/thread + pair shfl reduce) -- the previous version loaded+meaned the whole
// 32KB image per block (30x redundant global read, 8x redundant VALU).
// Each wave owns 2 output rows x 8 cols, processed as two q-groups of 4 cols, with
// 16 ds_read_b128 broadcast window loads per group. Lane = filter -> 256B coalesced stores.

#define STRIPES 15

__global__ __launch_bounds__(256, 4) void spectral_conv_kernel(
    const float* __restrict__ inputs,   // (64,32,32,8)
    const float* __restrict__ om_diag,  // (64,3)
    const float* __restrict__ om_triu,  // (1,192)
    const float* __restrict__ om_tril,  // (1,192)
    const float* __restrict__ lam_in,   // (3,1)
    const float* __restrict__ lam_out,  // (1,3)
    const float* __restrict__ enc,      // (1,1024)
    const float* __restrict__ dec,      // (900,1)
    float* __restrict__ out)            // (64,30,30,64)
{
    __shared__ float4 up4[34];  // 4 rows x 32 cols = 128 floats + 8 pad (tail window reads)
    __shared__ float4 ue4[34];
    float* up_s = (float*)up4;
    float* ue_s = (float*)ue4;

    const int tid    = threadIdx.x;
    const int b      = (int)blockIdx.x & 63;
    const int stripe = (int)blockIdx.x >> 6;   // 0..14
    const int r0     = stripe * 2;             // output rows r0, r0+1; input rows r0..r0+3

    // ---- Phase 1: channel mean (C=8) of the 4 needed input rows into LDS ----
    // Stripe input = 4*32 positions * 8 ch = 1024 floats = 256 float4.
    // Thread t loads float4 #t (fully coalesced 4KB), pair (2p,2p+1) holds position p.
    const float4* src = (const float4*)(inputs + ((size_t)b * 1024 + (size_t)r0 * 32) * 8);
    float4 v = src[tid];
    float s = v.x + v.y + v.z + v.w;
    s += __shfl_xor(s, 1);   // lanes 2p,2p+1 now both hold the 8-channel sum

    // ---- Per-lane filter weights (independent scalar/vector loads; overlap phase 1) ----
    const int f   = tid & 63;
    const int wid = tid >> 6;
    const float li0 = lam_in[0],  li1 = lam_in[1],  li2 = lam_in[2];
    const float lo0 = lam_out[0], lo1 = lam_out[1], lo2 = lam_out[2];
    const float w00 = om_diag[f * 3 + 0] * (li0 - lo0);
    const float w01 = om_triu[f * 3 + 0] * (li0 - lo1);
    const float w02 = om_triu[f * 3 + 1] * (li0 - lo2);
    const float w10 = om_tril[f * 3 + 0] * (li1 - lo0);
    const float w11 = om_diag[f * 3 + 1] * (li1 - lo1);
    const float w12 = om_triu[f * 3 + 2] * (li1 - lo2);
    const float w20 = om_tril[f * 3 + 1] * (li2 - lo0);
    const float w21 = om_tril[f * 3 + 2] * (li2 - lo1);
    const float w22 = om_diag[f * 3 + 2] * (li2 - lo2);

    if ((tid & 1) == 0) {
        int m = tid >> 1;                 // 0..127: local position = rowlocal*32 + col
        float u = s * 0.125f;
        up_s[m] = u;
        ue_s[m] = u * enc[r0 * 32 + m];   // global n = (r0+rowlocal)*32 + col
    }
    if (tid < 8) { up_s[128 + tid] = 0.0f; ue_s[128 + tid] = 0.0f; }  // zero pad
    __syncthreads();

    // ---- Phase 2: each wave = 2 output rows x 8 cols (two q-groups of 4) ----
    const int cb    = wid * 8;            // 0,8,16,24
    const int prow0 = r0 * 30;
    float* outb = out + (size_t)b * (900 * 64);

    #pragma unroll
    for (int g = 0; g < 2; ++g) {
        const int c0 = cb + g * 4;        // col of q=0 in this group (c0 % 4 == 0)

        // Stage 4 row-windows x 8 floats as b128 broadcasts
        float Ur[4][8], Er[4][8];
        #pragma unroll
        for (int rw = 0; rw < 4; ++rw) {
            int b4 = (rw * 32 + c0) >> 2;
            *(float4*)&Ur[rw][0] = up4[b4];
            *(float4*)&Ur[rw][4] = up4[b4 + 1];
            *(float4*)&Er[rw][0] = ue4[b4];
            *(float4*)&Er[rw][4] = ue4[b4 + 1];
        }

        #pragma unroll
        for (int q = 0; q < 4; ++q) {
            const int col = c0 + q;
            if (col < 30) {               // wave-uniform predicate (only wid=3,g=1 tail)
                // output row r0 (tap rows 0,1,2)
                float s1 = w00 * Er[0][q];
                float s2 = w00 * Ur[0][q];
                s1 = fmaf(w01, Er[0][q+1], s1);  s2 = fmaf(w01, Ur[0][q+1], s2);
                s1 = fmaf(w02, Er[0][q+2], s1);  s2 = fmaf(w02, Ur[0][q+2], s2);
                s1 = fmaf(w10, Er[1][q  ], s1);  s2 = fmaf(w10, Ur[1][q  ], s2);
                s1 = fmaf(w11, Er[1][q+1], s1);  s2 = fmaf(w11, Ur[1][q+1], s2);
                s1 = fmaf(w12, Er[1][q+2], s1);  s2 = fmaf(w12, Ur[1][q+2], s2);
                s1 = fmaf(w20, Er[2][q  ], s1);  s2 = fmaf(w20, Ur[2][q  ], s2);
                s1 = fmaf(w21, Er[2][q+1], s1);  s2 = fmaf(w21, Ur[2][q+1], s2);
                s1 = fmaf(w22, Er[2][q+2], s1);  s2 = fmaf(w22, Ur[2][q+2], s2);
                const int p0 = prow0 + col;
                float dl0 = dec[p0];
                outb[(size_t)p0 * 64 + f] = fmaxf(fmaf(-dl0, s2, s1), 0.0f);

                // output row r0+1 (tap rows 1,2,3)
                float t1 = w00 * Er[1][q];
                float t2 = w00 * Ur[1][q];
                t1 = fmaf(w01, Er[1][q+1], t1);  t2 = fmaf(w01, Ur[1][q+1], t2);
                t1 = fmaf(w02, Er[1][q+2], t1);  t2 = fmaf(w02, Ur[1][q+2], t2);
                t1 = fmaf(w10, Er[2][q  ], t1);  t2 = fmaf(w10, Ur[2][q  ], t2);
                t1 = fmaf(w11, Er[2][q+1], t1);  t2 = fmaf(w11, Ur[2][q+1], t2);
                t1 = fmaf(w12, Er[2][q+2], t1);  t2 = fmaf(w12, Ur[2][q+2], t2);
                t1 = fmaf(w20, Er[3][q  ], t1);  t2 = fmaf(w20, Ur[3][q  ], t2);
                t1 = fmaf(w21, Er[3][q+1], t1);  t2 = fmaf(w21, Ur[3][q+1], t2);
                t1 = fmaf(w22, Er[3][q+2], t1);  t2 = fmaf(w22, Ur[3][q+2], t2);
                float dl1 = dec[p0 + 30];
                outb[(size_t)(p0 + 30) * 64 + f] = fmaxf(fmaf(-dl1, t2, t1), 0.0f);
            }
        }
    }
}

extern "C" void kernel_launch(void* const* d_in, const int* in_sizes, int n_in,
                              void* d_out, int out_size, void* d_ws, size_t ws_size,
                              hipStream_t stream) {
    const float* inputs  = (const float*)d_in[0];
    const float* om_diag = (const float*)d_in[1];
    const float* om_triu = (const float*)d_in[2];
    const float* om_tril = (const float*)d_in[3];
    const float* lam_in  = (const float*)d_in[4];
    const float* lam_out = (const float*)d_in[5];
    const float* enc     = (const float*)d_in[6];
    const float* dec     = (const float*)d_in[7];
    float* out = (float*)d_out;

    dim3 grid(64 * STRIPES);
    dim3 block(256);
    spectral_conv_kernel<<<grid, block, 0, stream>>>(
        inputs, om_diag, om_triu, om_tril, lam_in, lam_out, enc, dec, out);
}